// Round 1
// 1724.091 us; speedup vs baseline: 1.0144x; 1.0144x over previous
//
#include <hip/hip_runtime.h>
#include <math.h>

// ---------------------------------------------------------------------------
// Swin block: B=64 H=W=56 C=256 WIN=7 SHIFT=3 HEADS=8 HD=32.
// Input/output dtype (fp32 vs bf16) detected at runtime; bf16 MFMA pipeline.
// Round 4: MLP v3 — swapped GEMM1 (C^T: vectorized Hs writes), A&S erf-GELU,
// double-buffered global_load_lds staging (pre-swizzled w1 chunks), raw
// s_barrier pipeline with 2 barriers/chunk. Other kernels unchanged.
// ---------------------------------------------------------------------------

typedef __attribute__((ext_vector_type(8))) short bf16x8;   // 8 bf16 = 4 VGPRs
typedef __attribute__((ext_vector_type(4))) float f32x4;

#define NTOK 200704   // 64*56*56
#define NN   49
#define NPARAM 4680   // fp32 param block element count

__device__ __forceinline__ float bf2f(unsigned short u) {
    union { unsigned int i; float f; } v; v.i = ((unsigned)u) << 16; return v.f;
}
__device__ __forceinline__ unsigned short f2bf(float f) {
    union { float fv; unsigned int i; } v; v.fv = f;
    return (unsigned short)((v.i + 0x7fffu + ((v.i >> 16) & 1u)) >> 16);  // RNE
}

// async global->LDS 16B (wave-uniform dest base + lane*16 pattern required)
__device__ __forceinline__ void gload_lds16(const unsigned short* g, unsigned short* l) {
    __builtin_amdgcn_global_load_lds(
        (const __attribute__((address_space(1))) unsigned int*)g,
        (__attribute__((address_space(3))) unsigned int*)l, 16, 0, 0);
}

// A&S 7.1.26 erf, |eps|<1.5e-7; gelu(v)=0.5v+0.5|v|*erf(|v|/sqrt2)*sgn-fold
__device__ __forceinline__ float gelu_erf(float v) {
    float av = fabsf(v);
    float x = av * 0.70710678118654752f;
    float t = __builtin_amdgcn_rcpf(fmaf(x, 0.3275911f, 1.0f));
    float p = fmaf(1.061405429f, t, -1.453152027f);
    p = fmaf(p, t, 1.421413741f);
    p = fmaf(p, t, -0.284496736f);
    p = fmaf(p, t, 0.254829592f);
    p = p * t;
    float ex = __builtin_amdgcn_exp2f(x * x * -1.4426950408889634f);
    float E = fmaf(-p, ex, 1.0f);          // erf(|v|/sqrt2)
    return fmaf(0.5f * av, E, 0.5f * v);
}

// ------------------------------ dtype detector -----------------------------
__global__ void detect_kernel(const unsigned short* __restrict__ xu, int* flag) {
    int ln = threadIdx.x;  // 64 threads
    int sane = 0;
    #pragma unroll
    for (int t = 0; t < 16; t++) {
        unsigned u = xu[(ln * 16 + t) * 2];
        unsigned e = (u >> 7) & 0xFF;
        sane += (e >= 0x60 && e <= 0x90) ? 1 : 0;
    }
    #pragma unroll
    for (int off = 32; off; off >>= 1) sane += __shfl_xor(sane, off);
    if (ln == 0) *flag = (sane < 614) ? 1 : 0;
}

__device__ __forceinline__ float ld_any(const void* p, int j, int f) {
    return f ? ((const float*)p)[j] : bf2f(((const unsigned short*)p)[j]);
}

// ------------------------ small params -> fp32 block -----------------------
__global__ void convert_params_kernel(
    const void* ln1_g, const void* ln1_b, const void* qkv_b, const void* proj_b,
    const void* ln2_g, const void* ln2_b, const void* b1, const void* b2,
    const void* rpb, const int* __restrict__ flag, float* __restrict__ dst) {
    int i = blockIdx.x * 256 + threadIdx.x;
    if (i >= NPARAM) return;
    int f = *flag;
    const void* src; int j;
    if      (i < 256)  { src = ln1_g;  j = i; }
    else if (i < 512)  { src = ln1_b;  j = i - 256; }
    else if (i < 1280) { src = qkv_b;  j = i - 512; }
    else if (i < 1536) { src = proj_b; j = i - 1280; }
    else if (i < 1792) { src = ln2_g;  j = i - 1536; }
    else if (i < 2048) { src = ln2_b;  j = i - 1792; }
    else if (i < 3072) { src = b1;     j = i - 2048; }
    else if (i < 3328) { src = b2;     j = i - 3072; }
    else               { src = rpb;    j = i - 3328; }
    dst[i] = ld_any(src, j, f);
}

// --------------------- weight transpose (any dtype -> bf16) ----------------
// in: (K,N) row-major -> out: (N,K) row-major bf16
__global__ void transpose_any(const void* __restrict__ in,
                              unsigned short* __restrict__ out, int K, int N,
                              const int* __restrict__ flag) {
    int f = *flag;
    int idx = blockIdx.x * 256 + threadIdx.x;
    if (idx < K * N) {
        int k = idx / N, n = idx - k * N;
        out[n * K + k] = f2bf(ld_any(in, idx, f));
    }
}

// ---- w1 (256,1024) -> 32 chunks of [32 h-rows x 256 k], XOR-pre-swizzled ---
// LDS image per chunk is 16KB linear; read applies k ^= (row&7)<<3 (shorts).
__global__ void relayout_w1(const void* __restrict__ in,
                            unsigned short* __restrict__ out,
                            const int* __restrict__ flag) {
    int f = *flag;
    int idx = blockIdx.x * 256 + threadIdx.x;  // over 256*1024, in elem (k,h)
    if (idx < 256 * 1024) {
        int k = idx >> 10, h = idx & 1023;
        int c = h >> 5, r = h & 31;
        int ks = k ^ ((r & 7) << 3);           // pre-swizzle within 256-short row
        out[c * 8192 + r * 256 + ks] = f2bf(ld_any(in, idx, f));
    }
}

// ------------- w2 (1024,256) -> k-chunk-major blocks (32 x [256n x 32k]) ---
// dst[c*8192 + n*32 + kk] = w2[(c*32+kk)*256 + n]  (16KB contiguous per chunk)
__global__ void relayout_w2(const void* __restrict__ in,
                            unsigned short* __restrict__ out,
                            const int* __restrict__ flag) {
    int f = *flag;
    int idx = blockIdx.x * 256 + threadIdx.x;  // over 1024*256
    if (idx < 1024 * 256) {
        int k = idx >> 8, n = idx & 255;
        int c = k >> 5, kk = k & 31;
        out[c * 8192 + n * 32 + kk] = f2bf(ld_any(in, idx, f));
    }
}

// ------------------------- LN1 + shift + window partition ------------------
__global__ __launch_bounds__(256) void ln1_window_kernel(
    const void* __restrict__ x, const float* __restrict__ paramsF,
    unsigned short* __restrict__ y, const int* __restrict__ flag) {
    int f = *flag;
    int wv = threadIdx.x >> 6, ln = threadIdx.x & 63;
    int tok = blockIdx.x * 4 + wv;
    float v0, v1, v2, v3;
    if (f) {
        float4 pv = *(const float4*)((const float*)x + (size_t)tok * 256 + ln * 4);
        v0 = pv.x; v1 = pv.y; v2 = pv.z; v3 = pv.w;
    } else {
        ushort4 pv = *(const ushort4*)((const unsigned short*)x + (size_t)tok * 256 + ln * 4);
        v0 = bf2f(pv.x); v1 = bf2f(pv.y); v2 = bf2f(pv.z); v3 = bf2f(pv.w);
    }
    float s = v0 + v1 + v2 + v3;
    float sq = v0 * v0 + v1 * v1 + v2 * v2 + v3 * v3;
    #pragma unroll
    for (int off = 32; off; off >>= 1) { s += __shfl_xor(s, off); sq += __shfl_xor(sq, off); }
    float mu = s * (1.f / 256.f);
    float rs = rsqrtf(fmaxf(sq * (1.f / 256.f) - mu * mu, 0.f) + 1e-5f);
    float4 gv = *(const float4*)(paramsF + ln * 4);        // ln1_g
    float4 bv = *(const float4*)(paramsF + 256 + ln * 4);  // ln1_b
    int bb = tok / 3136, hw = tok - bb * 3136;
    int h = hw / 56, w = hw - h * 56;
    int hp = h - 3; hp += (hp < 0) ? 56 : 0;
    int wp = w - 3; wp += (wp < 0) ? 56 : 0;
    int win = (hp / 7) * 8 + (wp / 7);
    int n = (hp % 7) * 7 + (wp % 7);
    size_t drow = ((size_t)bb * 64 + win) * NN + n;
    ushort4 o;
    o.x = f2bf((v0 - mu) * rs * gv.x + bv.x);
    o.y = f2bf((v1 - mu) * rs * gv.y + bv.y);
    o.z = f2bf((v2 - mu) * rs * gv.z + bv.z);
    o.w = f2bf((v3 - mu) * rs * gv.w + bv.w);
    *(ushort4*)(y + drow * 256 + ln * 4) = o;
}

// ------------------------------ GEMM core (K=256) --------------------------
__device__ __forceinline__ void gemm_core_k256(
    const unsigned short* __restrict__ A, const unsigned short* __restrict__ Bt,
    int rowBase, int colBase, unsigned short* As, unsigned short* Bs, f32x4 acc[2][4]) {
    const int tid = threadIdx.x;
    const int wv = tid >> 6, ln = tid & 63;
    const int m16 = ln & 15, q4 = ln >> 4;
    const int ar = tid >> 1, ah = (tid & 1) * 32;
    const int br = tid >> 2, bp = (tid & 3) * 16;
    for (int kb = 0; kb < 256; kb += 64) {
        const unsigned short* ag = A + (size_t)(rowBase + ar) * 256 + kb + ah;
        unsigned short* asd = As + ar * 72 + ah;
        #pragma unroll
        for (int i = 0; i < 4; i++)
            *(bf16x8*)(asd + i * 8) = *(const bf16x8*)(ag + i * 8);
        const unsigned short* bg = Bt + (size_t)(colBase + br) * 256 + kb + bp;
        unsigned short* bsd = Bs + br * 72 + bp;
        #pragma unroll
        for (int i = 0; i < 2; i++)
            *(bf16x8*)(bsd + i * 8) = *(const bf16x8*)(bg + i * 8);
        __syncthreads();
        #pragma unroll
        for (int ks = 0; ks < 64; ks += 32) {
            bf16x8 af[2], bfr[4];
            #pragma unroll
            for (int rt = 0; rt < 2; rt++)
                af[rt] = *(const bf16x8*)(As + (wv * 32 + rt * 16 + m16) * 72 + ks + q4 * 8);
            #pragma unroll
            for (int ct = 0; ct < 4; ct++)
                bfr[ct] = *(const bf16x8*)(Bs + (ct * 16 + m16) * 72 + ks + q4 * 8);
            #pragma unroll
            for (int rt = 0; rt < 2; rt++)
                #pragma unroll
                for (int ct = 0; ct < 4; ct++)
                    acc[rt][ct] = __builtin_amdgcn_mfma_f32_16x16x32_bf16(
                        af[rt], bfr[ct], acc[rt][ct], 0, 0, 0);
        }
        __syncthreads();
    }
}

// ------------------------------- GEMM: QKV ---------------------------------
__global__ __launch_bounds__(256) void gemm_qkv_kernel(
    const unsigned short* __restrict__ A, const unsigned short* __restrict__ Bt,
    const float* __restrict__ bias,  // qkv_b fp32 (768)
    unsigned short* __restrict__ out) {
    __shared__ unsigned short As[128 * 72];
    __shared__ unsigned short Bs[64 * 72];
    const int ln = threadIdx.x & 63, wv = threadIdx.x >> 6;
    const int m16 = ln & 15, q4 = ln >> 4;
    const int rowBase = blockIdx.y * 128, colBase = blockIdx.x * 64;
    f32x4 acc[2][4];
    #pragma unroll
    for (int i = 0; i < 2; i++)
        #pragma unroll
        for (int j = 0; j < 4; j++)
            #pragma unroll
            for (int r = 0; r < 4; r++) acc[i][j][r] = 0.f;
    gemm_core_k256(A, Bt, rowBase, colBase, As, Bs, acc);
    #pragma unroll
    for (int rt = 0; rt < 2; rt++)
        #pragma unroll
        for (int ct = 0; ct < 4; ct++) {
            int col = colBase + ct * 16 + m16;
            float bs = bias[col];
            float scale = (col < 256) ? 0.17677669529663689f : 1.0f;  // q * HD^-0.5
            #pragma unroll
            for (int r = 0; r < 4; r++) {
                int row = rowBase + wv * 32 + rt * 16 + q4 * 4 + r;
                out[(size_t)row * 768 + col] = f2bf((acc[rt][ct][r] + bs) * scale);
            }
        }
}

// ------------------------- GEMM: proj + scatter + residual -----------------
__global__ __launch_bounds__(256) void gemm_proj_kernel(
    const unsigned short* __restrict__ A, const unsigned short* __restrict__ Bt,
    const float* __restrict__ bias,  // proj_b fp32
    const void* __restrict__ xin,    // x natural order (flag dtype)
    unsigned short* __restrict__ x2, const int* __restrict__ flag) {
    __shared__ unsigned short As[128 * 72];
    __shared__ unsigned short Bs[64 * 72];
    const int f = *flag;
    const int ln = threadIdx.x & 63, wv = threadIdx.x >> 6;
    const int m16 = ln & 15, q4 = ln >> 4;
    const int rowBase = blockIdx.y * 128, colBase = blockIdx.x * 64;
    f32x4 acc[2][4];
    #pragma unroll
    for (int i = 0; i < 2; i++)
        #pragma unroll
        for (int j = 0; j < 4; j++)
            #pragma unroll
            for (int r = 0; r < 4; r++) acc[i][j][r] = 0.f;
    gemm_core_k256(A, Bt, rowBase, colBase, As, Bs, acc);
    #pragma unroll
    for (int rt = 0; rt < 2; rt++)
        #pragma unroll
        for (int r = 0; r < 4; r++) {
            int row = rowBase + wv * 32 + rt * 16 + q4 * 4 + r;  // window-order token
            int win = row / NN, n = row - win * NN;
            int bb = win >> 6, wl = win & 63;
            int i7 = n / 7, j7 = n - i7 * 7;
            int hp = (wl >> 3) * 7 + i7 + 3; if (hp >= 56) hp -= 56;  // un-shift
            int wp = (wl & 7) * 7 + j7 + 3;  if (wp >= 56) wp -= 56;
            size_t drow = ((size_t)bb * 3136 + hp * 56 + wp) * 256;
            #pragma unroll
            for (int ct = 0; ct < 4; ct++) {
                int col = colBase + ct * 16 + m16;
                float v = acc[rt][ct][r] + bias[col] + ld_any(xin, drow + col, f);
                x2[drow + col] = f2bf(v);
            }
        }
}

// ------------------------------- attention ---------------------------------
__global__ __launch_bounds__(256) void attn_kernel(
    const unsigned short* __restrict__ qkv,  // (NTOK,768): [q|k|v] x head x d
    const float* __restrict__ rpbF,          // (169*8) fp32
    unsigned short* __restrict__ o) {        // (NTOK,256) window order
    __shared__ unsigned short Qs[49 * 40], Ks[49 * 40], Vs[49 * 40];
    __shared__ float S[49 * 52];
    int tid = threadIdx.x;
    int win = blockIdx.x >> 3, head = blockIdx.x & 7;
    size_t base = (size_t)win * 49 * 768 + head * 32;
    if (tid < 196) {
        int i = tid >> 2, part = (tid & 3) * 8;
        *(bf16x8*)(Qs + i * 40 + part) = *(const bf16x8*)(qkv + base + (size_t)i * 768 + part);
        *(bf16x8*)(Ks + i * 40 + part) = *(const bf16x8*)(qkv + base + 256 + (size_t)i * 768 + part);
        *(bf16x8*)(Vs + i * 40 + part) = *(const bf16x8*)(qkv + base + 512 + (size_t)i * 768 + part);
    }
    __syncthreads();
    int wl = win & 63;
    int wh0 = (wl >> 3) * 7, ww0 = (wl & 7) * 7;
    for (int e = tid; e < 2401; e += 256) {
        int i = e / 49, j = e - i * 49;
        float a = 0.f;
        #pragma unroll
        for (int dd = 0; dd < 32; dd += 8) {
            bf16x8 qv = *(const bf16x8*)(Qs + i * 40 + dd);
            bf16x8 kv = *(const bf16x8*)(Ks + j * 40 + dd);
            #pragma unroll
            for (int u = 0; u < 8; u++)
                a += bf2f((unsigned short)qv[u]) * bf2f((unsigned short)kv[u]);
        }
        int ir = i / 7, ic = i - ir * 7, jr = j / 7, jc = j - jr * 7;
        a += rpbF[((ir - jr + 6) * 13 + (ic - jc + 6)) * 8 + head];
        int hi = wh0 + ir, wi = ww0 + ic, hj = wh0 + jr, wj = ww0 + jc;
        int ci = (hi < 49 ? 0 : (hi < 53 ? 3 : 6)) + (wi < 49 ? 0 : (wi < 53 ? 1 : 2));
        int cj = (hj < 49 ? 0 : (hj < 53 ? 3 : 6)) + (wj < 49 ? 0 : (wj < 53 ? 1 : 2));
        if (ci != cj) a -= 100.f;
        S[i * 52 + j] = a;
    }
    __syncthreads();
    if (tid < 49) {
        float m = -1e30f;
        for (int j = 0; j < 49; j++) m = fmaxf(m, S[tid * 52 + j]);
        float s = 0.f;
        for (int j = 0; j < 49; j++) { float e = expf(S[tid * 52 + j] - m); S[tid * 52 + j] = e; s += e; }
        float inv = 1.f / s;
        for (int j = 0; j < 49; j++) S[tid * 52 + j] *= inv;
    }
    __syncthreads();
    if (tid < 196) {
        int i = tid >> 2, dr = (tid & 3) * 8;
        float a[8];
        #pragma unroll
        for (int u = 0; u < 8; u++) a[u] = 0.f;
        for (int j = 0; j < 49; j++) {
            float pp = S[i * 52 + j];
            bf16x8 vv = *(const bf16x8*)(Vs + j * 40 + dr);
            #pragma unroll
            for (int u = 0; u < 8; u++) a[u] += pp * bf2f((unsigned short)vv[u]);
        }
        bf16x8 ov;
        #pragma unroll
        for (int u = 0; u < 8; u++) ov[u] = (short)f2bf(a[u]);
        *(bf16x8*)(o + ((size_t)win * 49 + i) * 256 + head * 32 + dr) = ov;
    }
}

// ---------------- fused LN2 + MLP + residual, v3 (pipelined) ---------------
// 64 tokens/block, 4 waves. LN2(x2) in regs. 32 hidden-chunks of 32:
//   GEMM1 swapped (C^T: col=token) -> A&S erf-gelu -> Hs (b64 writes)
//   -> GEMM2 partial into persistent acc2.
// Staging: double-buffered Bs1/Bs2 filled by global_load_lds one chunk ahead
// (w1 chunks pre-XOR-swizzled in relayout_w1; w2 chunks naturally clean).
// 2 raw s_barriers/chunk; vmcnt(0) waits only own prefetch (a full chunk of
// compute covers the L2 latency).
__global__ __launch_bounds__(256, 2) void mlp_fused_v3(
    const unsigned short* __restrict__ x2,
    const float* __restrict__ g2F, const float* __restrict__ b2lnF,
    const unsigned short* __restrict__ w1s,  // 32 chunks [32r x 256k] swizzled
    const float* __restrict__ b1F,
    const unsigned short* __restrict__ w2s,  // 32 chunks [256n x 32k]
    const float* __restrict__ b2F,
    void* __restrict__ out, const int* __restrict__ flag) {
    __shared__ __align__(16) unsigned short Bs1[2][32 * 256];  // 2 x 16KB
    __shared__ __align__(16) unsigned short Bs2[2][256 * 32];  // 2 x 16KB
    __shared__ __align__(16) unsigned short Hs[64 * 40];       // 5KB
    const int f = *flag;
    const int tid = threadIdx.x;
    const int wv = tid >> 6, ln = tid & 63;
    const int m16 = ln & 15, q4 = ln >> 4;
    const int tok0 = blockIdx.x * 64;

    // ---- issue chunk-0 staging first (overlaps LN2 compute below) ----
    {
        const unsigned short* s1 = w1s + tid * 8;
        const unsigned short* s2 = w2s + tid * 8;
        #pragma unroll
        for (int j = 0; j < 4; j++) {
            gload_lds16(s1 + j * 2048, &Bs1[0][tid * 8 + j * 2048]);
            gload_lds16(s2 + j * 2048, &Bs2[0][tid * 8 + j * 2048]);
        }
    }

    // ---- load x2 rows + LN2 -> areg (A/B-operand fragments, 8 k-steps) ----
    bf16x8 areg[8];
    {
        const unsigned short* xr = x2 + (size_t)(tok0 + wv * 16 + m16) * 256 + q4 * 8;
        #pragma unroll
        for (int ks = 0; ks < 8; ks++) areg[ks] = *(const bf16x8*)(xr + ks * 32);
        float s = 0.f, sq = 0.f;
        #pragma unroll
        for (int ks = 0; ks < 8; ks++)
            #pragma unroll
            for (int u = 0; u < 8; u++) {
                float v = bf2f((unsigned short)areg[ks][u]);
                s += v; sq += v * v;
            }
        s += __shfl_xor(s, 16); s += __shfl_xor(s, 32);
        sq += __shfl_xor(sq, 16); sq += __shfl_xor(sq, 32);
        float mu = s * (1.f / 256.f);
        float rs = rsqrtf(fmaxf(sq * (1.f / 256.f) - mu * mu, 0.f) + 1e-5f);
        #pragma unroll
        for (int ks = 0; ks < 8; ks++)
            #pragma unroll
            for (int u = 0; u < 8; u++) {
                int kidx = ks * 32 + q4 * 8 + u;
                float v = (bf2f((unsigned short)areg[ks][u]) - mu) * rs * g2F[kidx] + b2lnF[kidx];
                areg[ks][u] = (short)f2bf(v);
            }
    }

    f32x4 acc2[4][4];
    #pragma unroll
    for (int rt = 0; rt < 4; rt++)
        #pragma unroll
        for (int ct = 0; ct < 4; ct++)
            #pragma unroll
            for (int r = 0; r < 4; r++) acc2[rt][ct][r] = 0.f;

    #pragma unroll 1
    for (int c = 0; c < 32; ++c) {
        const int cur = c & 1;
        // own prefetch for chunk c must have landed; then block-wide handoff:
        // after this barrier, everyone is done reading buf[cur^1] and Hs(c-1).
        asm volatile("s_waitcnt vmcnt(0)" ::: "memory");
        __builtin_amdgcn_s_barrier();
        __builtin_amdgcn_sched_barrier(0);

        // ---- issue staging for chunk c+1 into the other buffer ----
        if (c + 1 < 32) {
            const unsigned short* s1 = w1s + (size_t)(c + 1) * 8192 + tid * 8;
            const unsigned short* s2 = w2s + (size_t)(c + 1) * 8192 + tid * 8;
            unsigned short* d1 = &Bs1[cur ^ 1][tid * 8];
            unsigned short* d2 = &Bs2[cur ^ 1][tid * 8];
            #pragma unroll
            for (int j = 0; j < 4; j++) {
                gload_lds16(s1 + j * 2048, d1 + j * 2048);
                gload_lds16(s2 + j * 2048, d2 + j * 2048);
            }
        }
        __builtin_amdgcn_sched_barrier(0);

        // ---- GEMM1 swapped: acc1[ct] = C[hidden=q4*4+r(+16ct)][token=m16] ----
        f32x4 acc1[2];
        #pragma unroll
        for (int ct = 0; ct < 2; ct++)
            #pragma unroll
            for (int r = 0; r < 4; r++) acc1[ct][r] = 0.f;
        const unsigned short* b1base = &Bs1[cur][0];
        #pragma unroll
        for (int ks = 0; ks < 8; ks++) {
            int kidx = (ks * 32 + q4 * 8) ^ ((m16 & 7) << 3);  // un-swizzle
            #pragma unroll
            for (int ct = 0; ct < 2; ct++) {
                bf16x8 wfr = *(const bf16x8*)(b1base + (ct * 16 + m16) * 256 + kidx);
                acc1[ct] = __builtin_amdgcn_mfma_f32_16x16x32_bf16(wfr, areg[ks], acc1[ct], 0, 0, 0);
            }
        }

        // ---- bias + gelu, pack 4 consecutive hidden cols -> 1 b64 write ----
        #pragma unroll
        for (int ct = 0; ct < 2; ct++) {
            float4 bb = *(const float4*)(b1F + c * 32 + ct * 16 + q4 * 4);
            ushort4 o4;
            o4.x = f2bf(gelu_erf(acc1[ct][0] + bb.x));
            o4.y = f2bf(gelu_erf(acc1[ct][1] + bb.y));
            o4.z = f2bf(gelu_erf(acc1[ct][2] + bb.z));
            o4.w = f2bf(gelu_erf(acc1[ct][3] + bb.w));
            *(ushort4*)(Hs + (wv * 16 + m16) * 40 + ct * 16 + q4 * 4) = o4;
        }
        asm volatile("s_waitcnt lgkmcnt(0)" ::: "memory");
        __builtin_amdgcn_sched_barrier(0);
        __builtin_amdgcn_s_barrier();   // Hs(c) visible to all waves
        __builtin_amdgcn_sched_barrier(0);

        // ---- GEMM2 partial: K=32 chunk; wave w -> out cols [64w,+64) ----
        bf16x8 haf[4];
        #pragma unroll
        for (int rt = 0; rt < 4; rt++)
            haf[rt] = *(const bf16x8*)(Hs + (rt * 16 + m16) * 40 + q4 * 8);
        const unsigned short* b2base = &Bs2[cur][0];
        #pragma unroll
        for (int ct = 0; ct < 4; ct++) {
            bf16x8 bfr = *(const bf16x8*)(b2base + (wv * 64 + ct * 16 + m16) * 32 + q4 * 8);
            #pragma unroll
            for (int rt = 0; rt < 4; rt++)
                acc2[rt][ct] = __builtin_amdgcn_mfma_f32_16x16x32_bf16(haf[rt], bfr, acc2[rt][ct], 0, 0, 0);
        }
    }

    // ---- epilogue: + b2 + residual, store ----
    #pragma unroll
    for (int rt = 0; rt < 4; rt++)
        #pragma unroll
        for (int ct = 0; ct < 4; ct++) {
            int col = wv * 64 + ct * 16 + m16;
            float bb = b2F[col];
            #pragma unroll
            for (int r = 0; r < 4; r++) {
                int tokr = tok0 + rt * 16 + q4 * 4 + r;
                size_t idx = (size_t)tokr * 256 + col;
                float v = acc2[rt][ct][r] + bb + bf2f(x2[idx]);
                if (f) ((float*)out)[idx] = v;
                else   ((unsigned short*)out)[idx] = f2bf(v);
            }
        }
}

// ------------------------------- launcher ----------------------------------
extern "C" void kernel_launch(void* const* d_in, const int* in_sizes, int n_in,
                              void* d_out, int out_size, void* d_ws, size_t ws_size,
                              hipStream_t stream) {
    const void* x      = d_in[0];
    const void* qkv_w  = d_in[3];
    const void* proj_w = d_in[6];
    const void* w1     = d_in[10];
    const void* w2     = d_in[12];

    char* ws = (char*)d_ws;
    size_t off = 0;
    unsigned short* y = (unsigned short*)(ws + off);       // LN1 out; reused as attn out
    off += (size_t)NTOK * 256 * 2;
    size_t qkv_off = off;
    unsigned short* qkv = (unsigned short*)(ws + off);     // (NTOK,768) bf16
    off += (size_t)NTOK * 768 * 2;
    unsigned short* x2 = (unsigned short*)(ws + qkv_off);  // overlaps qkv (dead by then)
    unsigned short* o = y;                                 // overlaps y (dead after QKV GEMM)
    unsigned short* qkvWt = (unsigned short*)(ws + off); off += 768 * 256 * 2;
    unsigned short* projWt = (unsigned short*)(ws + off); off += 256 * 256 * 2;
    unsigned short* w1s = (unsigned short*)(ws + off); off += 1024 * 256 * 2;
    unsigned short* w2s = (unsigned short*)(ws + off); off += 256 * 1024 * 2;
    float* paramsF = (float*)(ws + off); off += NPARAM * 4;
    int* flag = (int*)(ws + off); off += 16;
    (void)ws_size; (void)in_sizes; (void)n_in; (void)out_size;

    detect_kernel<<<1, 64, 0, stream>>>((const unsigned short*)x, flag);
    convert_params_kernel<<<(NPARAM + 255) / 256, 256, 0, stream>>>(
        d_in[1], d_in[2], d_in[4], d_in[7], d_in[8], d_in[9], d_in[11], d_in[13],
        d_in[5], flag, paramsF);
    transpose_any<<<(256 * 768 + 255) / 256, 256, 0, stream>>>(qkv_w, qkvWt, 256, 768, flag);
    transpose_any<<<(256 * 256 + 255) / 256, 256, 0, stream>>>(proj_w, projWt, 256, 256, flag);
    relayout_w1<<<(256 * 1024 + 255) / 256, 256, 0, stream>>>(w1, w1s, flag);
    relayout_w2<<<(1024 * 256 + 255) / 256, 256, 0, stream>>>(w2, w2s, flag);

    ln1_window_kernel<<<NTOK / 4, 256, 0, stream>>>(x, paramsF, y, flag);
    gemm_qkv_kernel<<<dim3(768 / 64, NTOK / 128), 256, 0, stream>>>(y, qkvWt, paramsF + 512, qkv);
    attn_kernel<<<4096 * 8, 256, 0, stream>>>(qkv, paramsF + 3328, o);
    gemm_proj_kernel<<<dim3(256 / 64, NTOK / 128), 256, 0, stream>>>(
        o, projWt, paramsF + 1280, x, x2, flag);
    mlp_fused_v3<<<NTOK / 64, 256, 0, stream>>>(
        x2, paramsF + 1536, paramsF + 1792, w1s, paramsF + 2048, w2s, paramsF + 3072, d_out, flag);
}

// Round 2
// 1397.313 us; speedup vs baseline: 1.2517x; 1.2339x over previous
//
#include <hip/hip_runtime.h>
#include <math.h>

// ---------------------------------------------------------------------------
// Swin block: B=64 H=W=56 C=256 WIN=7 SHIFT=3 HEADS=8 HD=32.
// Input/output dtype (fp32 vs bf16) detected at runtime; bf16 MFMA pipeline.
// Round 5: attention rewritten on MFMA. One block per window; swapped QK^T
// (S^T = K·Q^T) so softmax is lane-local + 2 shfls and P stores are b64;
// bias+mask+key-padding folded into a precomputed f32 table (4 window
// classes x 8 heads x 49 x 64); V transposed once per block into LDS.
// ---------------------------------------------------------------------------

typedef __attribute__((ext_vector_type(8))) short bf16x8;   // 8 bf16 = 4 VGPRs
typedef __attribute__((ext_vector_type(4))) float f32x4;

#define NTOK 200704   // 64*56*56
#define NN   49
#define NPARAM 4680   // fp32 param block element count
#define TBL_ELEMS (4 * 8 * 49 * 64)

__device__ __forceinline__ float bf2f(unsigned short u) {
    union { unsigned int i; float f; } v; v.i = ((unsigned)u) << 16; return v.f;
}
__device__ __forceinline__ unsigned short f2bf(float f) {
    union { float fv; unsigned int i; } v; v.fv = f;
    return (unsigned short)((v.i + 0x7fffu + ((v.i >> 16) & 1u)) >> 16);  // RNE
}

// async global->LDS 16B (wave-uniform dest base + lane*16 pattern required)
__device__ __forceinline__ void gload_lds16(const unsigned short* g, unsigned short* l) {
    __builtin_amdgcn_global_load_lds(
        (const __attribute__((address_space(1))) unsigned int*)g,
        (__attribute__((address_space(3))) unsigned int*)l, 16, 0, 0);
}

// A&S 7.1.26 erf, |eps|<1.5e-7; gelu(v)=0.5v+0.5|v|*erf(|v|/sqrt2)*sgn-fold
__device__ __forceinline__ float gelu_erf(float v) {
    float av = fabsf(v);
    float x = av * 0.70710678118654752f;
    float t = __builtin_amdgcn_rcpf(fmaf(x, 0.3275911f, 1.0f));
    float p = fmaf(1.061405429f, t, -1.453152027f);
    p = fmaf(p, t, 1.421413741f);
    p = fmaf(p, t, -0.284496736f);
    p = fmaf(p, t, 0.254829592f);
    p = p * t;
    float ex = __builtin_amdgcn_exp2f(x * x * -1.4426950408889634f);
    float E = fmaf(-p, ex, 1.0f);          // erf(|v|/sqrt2)
    return fmaf(0.5f * av, E, 0.5f * v);
}

// ------------------------------ dtype detector -----------------------------
__global__ void detect_kernel(const unsigned short* __restrict__ xu, int* flag) {
    int ln = threadIdx.x;  // 64 threads
    int sane = 0;
    #pragma unroll
    for (int t = 0; t < 16; t++) {
        unsigned u = xu[(ln * 16 + t) * 2];
        unsigned e = (u >> 7) & 0xFF;
        sane += (e >= 0x60 && e <= 0x90) ? 1 : 0;
    }
    #pragma unroll
    for (int off = 32; off; off >>= 1) sane += __shfl_xor(sane, off);
    if (ln == 0) *flag = (sane < 614) ? 1 : 0;
}

__device__ __forceinline__ float ld_any(const void* p, int j, int f) {
    return f ? ((const float*)p)[j] : bf2f(((const unsigned short*)p)[j]);
}

// ------------------------ small params -> fp32 block -----------------------
__global__ void convert_params_kernel(
    const void* ln1_g, const void* ln1_b, const void* qkv_b, const void* proj_b,
    const void* ln2_g, const void* ln2_b, const void* b1, const void* b2,
    const void* rpb, const int* __restrict__ flag, float* __restrict__ dst) {
    int i = blockIdx.x * 256 + threadIdx.x;
    if (i >= NPARAM) return;
    int f = *flag;
    const void* src; int j;
    if      (i < 256)  { src = ln1_g;  j = i; }
    else if (i < 512)  { src = ln1_b;  j = i - 256; }
    else if (i < 1280) { src = qkv_b;  j = i - 512; }
    else if (i < 1536) { src = proj_b; j = i - 1280; }
    else if (i < 1792) { src = ln2_g;  j = i - 1536; }
    else if (i < 2048) { src = ln2_b;  j = i - 1792; }
    else if (i < 3072) { src = b1;     j = i - 2048; }
    else if (i < 3328) { src = b2;     j = i - 3072; }
    else               { src = rpb;    j = i - 3328; }
    dst[i] = ld_any(src, j, f);
}

// -------- combined bias+mask table: tbl[pat][head][q 49][k 64] f32 ---------
// pat = 2*(window row-boundary) + (window col-boundary). k>=49 -> -1e30
// (forces P=0 for padded keys). Mask: -100 where region(q)!=region(k).
__global__ void build_tbl_kernel(const float* __restrict__ rpbF,
                                 float* __restrict__ tbl) {
    int idx = blockIdx.x * 256 + threadIdx.x;
    if (idx >= TBL_ELEMS) return;
    int k = idx & 63;
    int q = (idx >> 6) % 49;
    int h = ((idx >> 6) / 49) & 7;
    int pat = idx / (64 * 49 * 8);
    float v;
    if (k >= 49) {
        v = -1e30f;
    } else {
        int ir = q / 7, ic = q - ir * 7, jr = k / 7, jc = k - jr * 7;
        v = rpbF[((ir - jr + 6) * 13 + (ic - jc + 6)) * 8 + h];
        int rb = pat >> 1, cb = pat & 1;
        int ci = (rb ? (ir < 4 ? 3 : 6) : 0) + (cb ? (ic < 4 ? 1 : 2) : 0);
        int cj = (rb ? (jr < 4 ? 3 : 6) : 0) + (cb ? (jc < 4 ? 1 : 2) : 0);
        if (ci != cj) v -= 100.f;
    }
    tbl[idx] = v;
}

// --------------------- weight transpose (any dtype -> bf16) ----------------
// in: (K,N) row-major -> out: (N,K) row-major bf16
__global__ void transpose_any(const void* __restrict__ in,
                              unsigned short* __restrict__ out, int K, int N,
                              const int* __restrict__ flag) {
    int f = *flag;
    int idx = blockIdx.x * 256 + threadIdx.x;
    if (idx < K * N) {
        int k = idx / N, n = idx - k * N;
        out[n * K + k] = f2bf(ld_any(in, idx, f));
    }
}

// ---- w1 (256,1024) -> 32 chunks of [32 h-rows x 256 k], XOR-pre-swizzled ---
__global__ void relayout_w1(const void* __restrict__ in,
                            unsigned short* __restrict__ out,
                            const int* __restrict__ flag) {
    int f = *flag;
    int idx = blockIdx.x * 256 + threadIdx.x;  // over 256*1024, in elem (k,h)
    if (idx < 256 * 1024) {
        int k = idx >> 10, h = idx & 1023;
        int c = h >> 5, r = h & 31;
        int ks = k ^ ((r & 7) << 3);           // pre-swizzle within 256-short row
        out[c * 8192 + r * 256 + ks] = f2bf(ld_any(in, idx, f));
    }
}

// ------------- w2 (1024,256) -> k-chunk-major blocks (32 x [256n x 32k]) ---
__global__ void relayout_w2(const void* __restrict__ in,
                            unsigned short* __restrict__ out,
                            const int* __restrict__ flag) {
    int f = *flag;
    int idx = blockIdx.x * 256 + threadIdx.x;  // over 1024*256
    if (idx < 1024 * 256) {
        int k = idx >> 8, n = idx & 255;
        int c = k >> 5, kk = k & 31;
        out[c * 8192 + n * 32 + kk] = f2bf(ld_any(in, idx, f));
    }
}

// ------------------------- LN1 + shift + window partition ------------------
__global__ __launch_bounds__(256) void ln1_window_kernel(
    const void* __restrict__ x, const float* __restrict__ paramsF,
    unsigned short* __restrict__ y, const int* __restrict__ flag) {
    int f = *flag;
    int wv = threadIdx.x >> 6, ln = threadIdx.x & 63;
    int tok = blockIdx.x * 4 + wv;
    float v0, v1, v2, v3;
    if (f) {
        float4 pv = *(const float4*)((const float*)x + (size_t)tok * 256 + ln * 4);
        v0 = pv.x; v1 = pv.y; v2 = pv.z; v3 = pv.w;
    } else {
        ushort4 pv = *(const ushort4*)((const unsigned short*)x + (size_t)tok * 256 + ln * 4);
        v0 = bf2f(pv.x); v1 = bf2f(pv.y); v2 = bf2f(pv.z); v3 = bf2f(pv.w);
    }
    float s = v0 + v1 + v2 + v3;
    float sq = v0 * v0 + v1 * v1 + v2 * v2 + v3 * v3;
    #pragma unroll
    for (int off = 32; off; off >>= 1) { s += __shfl_xor(s, off); sq += __shfl_xor(sq, off); }
    float mu = s * (1.f / 256.f);
    float rs = rsqrtf(fmaxf(sq * (1.f / 256.f) - mu * mu, 0.f) + 1e-5f);
    float4 gv = *(const float4*)(paramsF + ln * 4);        // ln1_g
    float4 bv = *(const float4*)(paramsF + 256 + ln * 4);  // ln1_b
    int bb = tok / 3136, hw = tok - bb * 3136;
    int h = hw / 56, w = hw - h * 56;
    int hp = h - 3; hp += (hp < 0) ? 56 : 0;
    int wp = w - 3; wp += (wp < 0) ? 56 : 0;
    int win = (hp / 7) * 8 + (wp / 7);
    int n = (hp % 7) * 7 + (wp % 7);
    size_t drow = ((size_t)bb * 64 + win) * NN + n;
    ushort4 o;
    o.x = f2bf((v0 - mu) * rs * gv.x + bv.x);
    o.y = f2bf((v1 - mu) * rs * gv.y + bv.y);
    o.z = f2bf((v2 - mu) * rs * gv.z + bv.z);
    o.w = f2bf((v3 - mu) * rs * gv.w + bv.w);
    *(ushort4*)(y + drow * 256 + ln * 4) = o;
}

// ------------------------------ GEMM core (K=256) --------------------------
__device__ __forceinline__ void gemm_core_k256(
    const unsigned short* __restrict__ A, const unsigned short* __restrict__ Bt,
    int rowBase, int colBase, unsigned short* As, unsigned short* Bs, f32x4 acc[2][4]) {
    const int tid = threadIdx.x;
    const int wv = tid >> 6, ln = tid & 63;
    const int m16 = ln & 15, q4 = ln >> 4;
    const int ar = tid >> 1, ah = (tid & 1) * 32;
    const int br = tid >> 2, bp = (tid & 3) * 16;
    for (int kb = 0; kb < 256; kb += 64) {
        const unsigned short* ag = A + (size_t)(rowBase + ar) * 256 + kb + ah;
        unsigned short* asd = As + ar * 72 + ah;
        #pragma unroll
        for (int i = 0; i < 4; i++)
            *(bf16x8*)(asd + i * 8) = *(const bf16x8*)(ag + i * 8);
        const unsigned short* bg = Bt + (size_t)(colBase + br) * 256 + kb + bp;
        unsigned short* bsd = Bs + br * 72 + bp;
        #pragma unroll
        for (int i = 0; i < 2; i++)
            *(bf16x8*)(bsd + i * 8) = *(const bf16x8*)(bg + i * 8);
        __syncthreads();
        #pragma unroll
        for (int ks = 0; ks < 64; ks += 32) {
            bf16x8 af[2], bfr[4];
            #pragma unroll
            for (int rt = 0; rt < 2; rt++)
                af[rt] = *(const bf16x8*)(As + (wv * 32 + rt * 16 + m16) * 72 + ks + q4 * 8);
            #pragma unroll
            for (int ct = 0; ct < 4; ct++)
                bfr[ct] = *(const bf16x8*)(Bs + (ct * 16 + m16) * 72 + ks + q4 * 8);
            #pragma unroll
            for (int rt = 0; rt < 2; rt++)
                #pragma unroll
                for (int ct = 0; ct < 4; ct++)
                    acc[rt][ct] = __builtin_amdgcn_mfma_f32_16x16x32_bf16(
                        af[rt], bfr[ct], acc[rt][ct], 0, 0, 0);
        }
        __syncthreads();
    }
}

// ------------------------------- GEMM: QKV ---------------------------------
__global__ __launch_bounds__(256) void gemm_qkv_kernel(
    const unsigned short* __restrict__ A, const unsigned short* __restrict__ Bt,
    const float* __restrict__ bias,  // qkv_b fp32 (768)
    unsigned short* __restrict__ out) {
    __shared__ unsigned short As[128 * 72];
    __shared__ unsigned short Bs[64 * 72];
    const int ln = threadIdx.x & 63, wv = threadIdx.x >> 6;
    const int m16 = ln & 15, q4 = ln >> 4;
    const int rowBase = blockIdx.y * 128, colBase = blockIdx.x * 64;
    f32x4 acc[2][4];
    #pragma unroll
    for (int i = 0; i < 2; i++)
        #pragma unroll
        for (int j = 0; j < 4; j++)
            #pragma unroll
            for (int r = 0; r < 4; r++) acc[i][j][r] = 0.f;
    gemm_core_k256(A, Bt, rowBase, colBase, As, Bs, acc);
    #pragma unroll
    for (int rt = 0; rt < 2; rt++)
        #pragma unroll
        for (int ct = 0; ct < 4; ct++) {
            int col = colBase + ct * 16 + m16;
            float bs = bias[col];
            float scale = (col < 256) ? 0.17677669529663689f : 1.0f;  // q * HD^-0.5
            #pragma unroll
            for (int r = 0; r < 4; r++) {
                int row = rowBase + wv * 32 + rt * 16 + q4 * 4 + r;
                out[(size_t)row * 768 + col] = f2bf((acc[rt][ct][r] + bs) * scale);
            }
        }
}

// ------------------------- GEMM: proj + scatter + residual -----------------
__global__ __launch_bounds__(256) void gemm_proj_kernel(
    const unsigned short* __restrict__ A, const unsigned short* __restrict__ Bt,
    const float* __restrict__ bias,  // proj_b fp32
    const void* __restrict__ xin,    // x natural order (flag dtype)
    unsigned short* __restrict__ x2, const int* __restrict__ flag) {
    __shared__ unsigned short As[128 * 72];
    __shared__ unsigned short Bs[64 * 72];
    const int f = *flag;
    const int ln = threadIdx.x & 63, wv = threadIdx.x >> 6;
    const int m16 = ln & 15, q4 = ln >> 4;
    const int rowBase = blockIdx.y * 128, colBase = blockIdx.x * 64;
    f32x4 acc[2][4];
    #pragma unroll
    for (int i = 0; i < 2; i++)
        #pragma unroll
        for (int j = 0; j < 4; j++)
            #pragma unroll
            for (int r = 0; r < 4; r++) acc[i][j][r] = 0.f;
    gemm_core_k256(A, Bt, rowBase, colBase, As, Bs, acc);
    #pragma unroll
    for (int rt = 0; rt < 2; rt++)
        #pragma unroll
        for (int r = 0; r < 4; r++) {
            int row = rowBase + wv * 32 + rt * 16 + q4 * 4 + r;  // window-order token
            int win = row / NN, n = row - win * NN;
            int bb = win >> 6, wl = win & 63;
            int i7 = n / 7, j7 = n - i7 * 7;
            int hp = (wl >> 3) * 7 + i7 + 3; if (hp >= 56) hp -= 56;  // un-shift
            int wp = (wl & 7) * 7 + j7 + 3;  if (wp >= 56) wp -= 56;
            size_t drow = ((size_t)bb * 3136 + hp * 56 + wp) * 256;
            #pragma unroll
            for (int ct = 0; ct < 4; ct++) {
                int col = colBase + ct * 16 + m16;
                float v = acc[rt][ct][r] + bias[col] + ld_any(xin, drow + col, f);
                x2[drow + col] = f2bf(v);
            }
        }
}

// --------------------------- attention (MFMA) ------------------------------
// One block = one window (49 tokens, 8 heads). 4 waves; wave w -> heads 2w,2w+1.
// S^T = K·Q^T (swapped) so lane holds contiguous keys per query: softmax is
// 15 in-lane ops + 2 shfls; P packs to b64 LDS writes. PV from Ps (A) and
// per-block transposed Vt (B). Padded keys killed by tbl=-1e30; Vt pad zeroed.
__global__ __launch_bounds__(256) void attn_mfma_kernel(
    const unsigned short* __restrict__ qkv,  // (NTOK,768): [q|k|v] x head x d
    const float* __restrict__ tbl,           // [4][8][49][64] f32
    unsigned short* __restrict__ o) {        // (NTOK,256) window order
    __shared__ __align__(16) unsigned short Vt[256 * 72];   // [d 256][tok 72]
    __shared__ __align__(16) unsigned short Ps[4][64 * 72]; // per-wave [q 64][k 72]
    const int tid = threadIdx.x;
    const int wv = tid >> 6, ln = tid & 63;
    const int m16 = ln & 15, q4 = ln >> 4;
    const int win = blockIdx.x;
    const size_t wbase = (size_t)win * 49 * 768;

    // ---- build Vt: all heads, tok-contiguous writes (conflict-free) ----
    #pragma unroll
    for (int i = 0; i < 8; i++) {
        int idx = i * 256 + tid;             // ch = idx>>6 (0..31), tok = idx&63
        int ch = idx >> 6, tok = idx & 63;
        if (tok < 49) {
            bf16x8 v = *(const bf16x8*)(qkv + wbase + (size_t)tok * 768 + 512 + ch * 8);
            #pragma unroll
            for (int u = 0; u < 8; u++)
                Vt[(ch * 8 + u) * 72 + tok] = (unsigned short)v[u];
        }
    }
    // zero pad columns 49..71 of row tid (P=0 there anyway; avoid 0*NaN)
    #pragma unroll
    for (int u = 0; u < 23; u++) Vt[tid * 72 + 49 + u] = 0;

    const int wl = win & 63;
    const int pat = (((wl >> 3) == 7) ? 2 : 0) + (((wl & 7) == 7) ? 1 : 0);
    __syncthreads();

    unsigned short* Pw = &Ps[wv][0];
    for (int hh = 0; hh < 2; hh++) {
        const int h = wv * 2 + hh;
        // ---- QK^T swapped: acc[kt][qt] = S^T tile (key row, query col) ----
        bf16x8 kf[4], qf[4];
        #pragma unroll
        for (int t = 0; t < 4; t++) {
            size_t rrow = wbase + (size_t)(t * 16 + m16) * 768 + h * 32 + q4 * 8;
            qf[t] = *(const bf16x8*)(qkv + rrow);
            kf[t] = *(const bf16x8*)(qkv + rrow + 256);
        }
        f32x4 acc[4][4];
        #pragma unroll
        for (int kt = 0; kt < 4; kt++)
            #pragma unroll
            for (int qt = 0; qt < 4; qt++) {
                #pragma unroll
                for (int r = 0; r < 4; r++) acc[kt][qt][r] = 0.f;
                acc[kt][qt] = __builtin_amdgcn_mfma_f32_16x16x32_bf16(
                    kf[kt], qf[qt], acc[kt][qt], 0, 0, 0);
            }

        // ---- softmax per query column (qt, m16); keys lane-local ----
        const float* tb = tbl + ((size_t)(pat * 8 + h) * 49) * 64;
        #pragma unroll
        for (int qt = 0; qt < 4; qt++) {
            int q = qt * 16 + m16;
            int qc = q < 49 ? q : 48;
            float s[4][4];
            float mx = -3e38f;
            #pragma unroll
            for (int kt = 0; kt < 4; kt++) {
                float4 tv = *(const float4*)(tb + qc * 64 + kt * 16 + q4 * 4);
                s[kt][0] = acc[kt][qt][0] + tv.x;
                s[kt][1] = acc[kt][qt][1] + tv.y;
                s[kt][2] = acc[kt][qt][2] + tv.z;
                s[kt][3] = acc[kt][qt][3] + tv.w;
                #pragma unroll
                for (int r = 0; r < 4; r++) mx = fmaxf(mx, s[kt][r]);
            }
            mx = fmaxf(mx, __shfl_xor(mx, 16));
            mx = fmaxf(mx, __shfl_xor(mx, 32));
            float sum = 0.f;
            #pragma unroll
            for (int kt = 0; kt < 4; kt++)
                #pragma unroll
                for (int r = 0; r < 4; r++) {
                    float e = __expf(s[kt][r] - mx);
                    s[kt][r] = e; sum += e;
                }
            sum += __shfl_xor(sum, 16);
            sum += __shfl_xor(sum, 32);
            float inv = 1.f / sum;
            #pragma unroll
            for (int kt = 0; kt < 4; kt++) {
                ushort4 p4;
                p4.x = f2bf(s[kt][0] * inv);
                p4.y = f2bf(s[kt][1] * inv);
                p4.z = f2bf(s[kt][2] * inv);
                p4.w = f2bf(s[kt][3] * inv);
                *(ushort4*)(Pw + q * 72 + kt * 16 + q4 * 4) = p4;
            }
        }

        // ---- PV: O[q][d] = P·V, A=Ps rows, B=Vt rows ----
        f32x4 po[4][2];
        #pragma unroll
        for (int mt = 0; mt < 4; mt++)
            #pragma unroll
            for (int nt = 0; nt < 2; nt++)
                #pragma unroll
                for (int r = 0; r < 4; r++) po[mt][nt][r] = 0.f;
        #pragma unroll
        for (int kstep = 0; kstep < 2; kstep++) {
            bf16x8 pa[4], vb[2];
            #pragma unroll
            for (int mt = 0; mt < 4; mt++)
                pa[mt] = *(const bf16x8*)(Pw + (mt * 16 + m16) * 72 + kstep * 32 + q4 * 8);
            #pragma unroll
            for (int nt = 0; nt < 2; nt++)
                vb[nt] = *(const bf16x8*)(Vt + (h * 32 + nt * 16 + m16) * 72 + kstep * 32 + q4 * 8);
            #pragma unroll
            for (int mt = 0; mt < 4; mt++)
                #pragma unroll
                for (int nt = 0; nt < 2; nt++)
                    po[mt][nt] = __builtin_amdgcn_mfma_f32_16x16x32_bf16(
                        pa[mt], vb[nt], po[mt][nt], 0, 0, 0);
        }

        // ---- store O (rows q<49); 16 lanes write 32B contiguous ----
        #pragma unroll
        for (int mt = 0; mt < 4; mt++)
            #pragma unroll
            for (int r = 0; r < 4; r++) {
                int q = mt * 16 + q4 * 4 + r;
                if (q < 49) {
                    size_t orow = ((size_t)win * 49 + q) * 256 + h * 32;
                    o[orow + m16]      = f2bf(po[mt][0][r]);
                    o[orow + 16 + m16] = f2bf(po[mt][1][r]);
                }
            }
    }
}

// ---------------- fused LN2 + MLP + residual, v3 (pipelined) ---------------
__global__ __launch_bounds__(256, 2) void mlp_fused_v3(
    const unsigned short* __restrict__ x2,
    const float* __restrict__ g2F, const float* __restrict__ b2lnF,
    const unsigned short* __restrict__ w1s,  // 32 chunks [32r x 256k] swizzled
    const float* __restrict__ b1F,
    const unsigned short* __restrict__ w2s,  // 32 chunks [256n x 32k]
    const float* __restrict__ b2F,
    void* __restrict__ out, const int* __restrict__ flag) {
    __shared__ __align__(16) unsigned short Bs1[2][32 * 256];  // 2 x 16KB
    __shared__ __align__(16) unsigned short Bs2[2][256 * 32];  // 2 x 16KB
    __shared__ __align__(16) unsigned short Hs[64 * 40];       // 5KB
    const int f = *flag;
    const int tid = threadIdx.x;
    const int wv = tid >> 6, ln = tid & 63;
    const int m16 = ln & 15, q4 = ln >> 4;
    const int tok0 = blockIdx.x * 64;

    // ---- issue chunk-0 staging first (overlaps LN2 compute below) ----
    {
        const unsigned short* s1 = w1s + tid * 8;
        const unsigned short* s2 = w2s + tid * 8;
        #pragma unroll
        for (int j = 0; j < 4; j++) {
            gload_lds16(s1 + j * 2048, &Bs1[0][tid * 8 + j * 2048]);
            gload_lds16(s2 + j * 2048, &Bs2[0][tid * 8 + j * 2048]);
        }
    }

    // ---- load x2 rows + LN2 -> areg (A/B-operand fragments, 8 k-steps) ----
    bf16x8 areg[8];
    {
        const unsigned short* xr = x2 + (size_t)(tok0 + wv * 16 + m16) * 256 + q4 * 8;
        #pragma unroll
        for (int ks = 0; ks < 8; ks++) areg[ks] = *(const bf16x8*)(xr + ks * 32);
        float s = 0.f, sq = 0.f;
        #pragma unroll
        for (int ks = 0; ks < 8; ks++)
            #pragma unroll
            for (int u = 0; u < 8; u++) {
                float v = bf2f((unsigned short)areg[ks][u]);
                s += v; sq += v * v;
            }
        s += __shfl_xor(s, 16); s += __shfl_xor(s, 32);
        sq += __shfl_xor(sq, 16); sq += __shfl_xor(sq, 32);
        float mu = s * (1.f / 256.f);
        float rs = rsqrtf(fmaxf(sq * (1.f / 256.f) - mu * mu, 0.f) + 1e-5f);
        #pragma unroll
        for (int ks = 0; ks < 8; ks++)
            #pragma unroll
            for (int u = 0; u < 8; u++) {
                int kidx = ks * 32 + q4 * 8 + u;
                float v = (bf2f((unsigned short)areg[ks][u]) - mu) * rs * g2F[kidx] + b2lnF[kidx];
                areg[ks][u] = (short)f2bf(v);
            }
    }

    f32x4 acc2[4][4];
    #pragma unroll
    for (int rt = 0; rt < 4; rt++)
        #pragma unroll
        for (int ct = 0; ct < 4; ct++)
            #pragma unroll
            for (int r = 0; r < 4; r++) acc2[rt][ct][r] = 0.f;

    #pragma unroll 1
    for (int c = 0; c < 32; ++c) {
        const int cur = c & 1;
        asm volatile("s_waitcnt vmcnt(0)" ::: "memory");
        __builtin_amdgcn_s_barrier();
        __builtin_amdgcn_sched_barrier(0);

        // ---- issue staging for chunk c+1 into the other buffer ----
        if (c + 1 < 32) {
            const unsigned short* s1 = w1s + (size_t)(c + 1) * 8192 + tid * 8;
            const unsigned short* s2 = w2s + (size_t)(c + 1) * 8192 + tid * 8;
            unsigned short* d1 = &Bs1[cur ^ 1][tid * 8];
            unsigned short* d2 = &Bs2[cur ^ 1][tid * 8];
            #pragma unroll
            for (int j = 0; j < 4; j++) {
                gload_lds16(s1 + j * 2048, d1 + j * 2048);
                gload_lds16(s2 + j * 2048, d2 + j * 2048);
            }
        }
        __builtin_amdgcn_sched_barrier(0);

        // ---- GEMM1 swapped: acc1[ct] = C[hidden][token=m16] ----
        f32x4 acc1[2];
        #pragma unroll
        for (int ct = 0; ct < 2; ct++)
            #pragma unroll
            for (int r = 0; r < 4; r++) acc1[ct][r] = 0.f;
        const unsigned short* b1base = &Bs1[cur][0];
        #pragma unroll
        for (int ks = 0; ks < 8; ks++) {
            int kidx = (ks * 32 + q4 * 8) ^ ((m16 & 7) << 3);  // un-swizzle
            #pragma unroll
            for (int ct = 0; ct < 2; ct++) {
                bf16x8 wfr = *(const bf16x8*)(b1base + (ct * 16 + m16) * 256 + kidx);
                acc1[ct] = __builtin_amdgcn_mfma_f32_16x16x32_bf16(wfr, areg[ks], acc1[ct], 0, 0, 0);
            }
        }

        // ---- bias + gelu, pack 4 consecutive hidden cols -> 1 b64 write ----
        #pragma unroll
        for (int ct = 0; ct < 2; ct++) {
            float4 bb = *(const float4*)(b1F + c * 32 + ct * 16 + q4 * 4);
            ushort4 o4;
            o4.x = f2bf(gelu_erf(acc1[ct][0] + bb.x));
            o4.y = f2bf(gelu_erf(acc1[ct][1] + bb.y));
            o4.z = f2bf(gelu_erf(acc1[ct][2] + bb.z));
            o4.w = f2bf(gelu_erf(acc1[ct][3] + bb.w));
            *(ushort4*)(Hs + (wv * 16 + m16) * 40 + ct * 16 + q4 * 4) = o4;
        }
        asm volatile("s_waitcnt lgkmcnt(0)" ::: "memory");
        __builtin_amdgcn_sched_barrier(0);
        __builtin_amdgcn_s_barrier();   // Hs(c) visible to all waves
        __builtin_amdgcn_sched_barrier(0);

        // ---- GEMM2 partial: K=32 chunk; wave w -> out cols [64w,+64) ----
        bf16x8 haf[4];
        #pragma unroll
        for (int rt = 0; rt < 4; rt++)
            haf[rt] = *(const bf16x8*)(Hs + (rt * 16 + m16) * 40 + q4 * 8);
        const unsigned short* b2base = &Bs2[cur][0];
        #pragma unroll
        for (int ct = 0; ct < 4; ct++) {
            bf16x8 bfr = *(const bf16x8*)(b2base + (wv * 64 + ct * 16 + m16) * 32 + q4 * 8);
            #pragma unroll
            for (int rt = 0; rt < 4; rt++)
                acc2[rt][ct] = __builtin_amdgcn_mfma_f32_16x16x32_bf16(haf[rt], bfr, acc2[rt][ct], 0, 0, 0);
        }
    }

    // ---- epilogue: + b2 + residual, store ----
    #pragma unroll
    for (int rt = 0; rt < 4; rt++)
        #pragma unroll
        for (int ct = 0; ct < 4; ct++) {
            int col = wv * 64 + ct * 16 + m16;
            float bb = b2F[col];
            #pragma unroll
            for (int r = 0; r < 4; r++) {
                int tokr = tok0 + rt * 16 + q4 * 4 + r;
                size_t idx = (size_t)tokr * 256 + col;
                float v = acc2[rt][ct][r] + bb + bf2f(x2[idx]);
                if (f) ((float*)out)[idx] = v;
                else   ((unsigned short*)out)[idx] = f2bf(v);
            }
        }
}

// ------------------------------- launcher ----------------------------------
extern "C" void kernel_launch(void* const* d_in, const int* in_sizes, int n_in,
                              void* d_out, int out_size, void* d_ws, size_t ws_size,
                              hipStream_t stream) {
    const void* x      = d_in[0];
    const void* qkv_w  = d_in[3];
    const void* proj_w = d_in[6];
    const void* w1     = d_in[10];
    const void* w2     = d_in[12];

    char* ws = (char*)d_ws;
    size_t off = 0;
    unsigned short* y = (unsigned short*)(ws + off);       // LN1 out; reused as attn out
    off += (size_t)NTOK * 256 * 2;
    size_t qkv_off = off;
    unsigned short* qkv = (unsigned short*)(ws + off);     // (NTOK,768) bf16
    off += (size_t)NTOK * 768 * 2;
    unsigned short* x2 = (unsigned short*)(ws + qkv_off);  // overlaps qkv (dead by then)
    unsigned short* o = y;                                 // overlaps y (dead after QKV GEMM)
    unsigned short* qkvWt = (unsigned short*)(ws + off); off += 768 * 256 * 2;
    unsigned short* projWt = (unsigned short*)(ws + off); off += 256 * 256 * 2;
    unsigned short* w1s = (unsigned short*)(ws + off); off += 1024 * 256 * 2;
    unsigned short* w2s = (unsigned short*)(ws + off); off += 256 * 1024 * 2;
    float* paramsF = (float*)(ws + off); off += NPARAM * 4;
    int* flag = (int*)(ws + off); off += 16;
    float* tbl = (float*)(ws + off); off += (size_t)TBL_ELEMS * 4;
    (void)ws_size; (void)in_sizes; (void)n_in; (void)out_size;

    detect_kernel<<<1, 64, 0, stream>>>((const unsigned short*)x, flag);
    convert_params_kernel<<<(NPARAM + 255) / 256, 256, 0, stream>>>(
        d_in[1], d_in[2], d_in[4], d_in[7], d_in[8], d_in[9], d_in[11], d_in[13],
        d_in[5], flag, paramsF);
    build_tbl_kernel<<<(TBL_ELEMS + 255) / 256, 256, 0, stream>>>(paramsF + 3328, tbl);
    transpose_any<<<(256 * 768 + 255) / 256, 256, 0, stream>>>(qkv_w, qkvWt, 256, 768, flag);
    transpose_any<<<(256 * 256 + 255) / 256, 256, 0, stream>>>(proj_w, projWt, 256, 256, flag);
    relayout_w1<<<(256 * 1024 + 255) / 256, 256, 0, stream>>>(w1, w1s, flag);
    relayout_w2<<<(1024 * 256 + 255) / 256, 256, 0, stream>>>(w2, w2s, flag);

    ln1_window_kernel<<<NTOK / 4, 256, 0, stream>>>(x, paramsF, y, flag);
    gemm_qkv_kernel<<<dim3(768 / 64, NTOK / 128), 256, 0, stream>>>(y, qkvWt, paramsF + 512, qkv);
    attn_mfma_kernel<<<4096, 256, 0, stream>>>(qkv, tbl, o);
    gemm_proj_kernel<<<dim3(256 / 64, NTOK / 128), 256, 0, stream>>>(
        o, projWt, paramsF + 1280, x, x2, flag);
    mlp_fused_v3<<<NTOK / 64, 256, 0, stream>>>(
        x2, paramsF + 1536, paramsF + 1792, w1s, paramsF + 2048, w2s, paramsF + 3072, d_out, flag);
}